// Round 7
// baseline (175.287 us; speedup 1.0000x reference)
//
#include <hip/hip_runtime.h>

// Problem: B=64, K=17, H=128, W=128, RATIO=0.25, SIGMA=2.0
constexpr int   HW     = 16384;
constexpr int   NT     = 512;            // threads per block; 1 block per slice
constexpr int   NWV    = 8;              // waves per block
constexpr int   V4     = 8;              // float4 groups per thread (32 elems/thread)
constexpr int   GTMAX  = 4096;           // #(v > thresh) for kthvalue rank 12288
constexpr int   NSLICE = 1088;           // 64*17
constexpr int   SLOTS  = 10;             // per-thread stash (window mean 1.12/thread)
constexpr int   SSTR   = 11;             // stash stride pad
constexpr int   BINS   = 1024;           // counting-refinement buckets
constexpr float LO0    = 0.735f;         // static bracket around 0.75-quantile of U(0,1)
constexpr float HI0    = 0.770f;         // runtime-validated; exact fallback otherwise
constexpr float BSCALE = (float)BINS / (HI0 - LO0);

__device__ __forceinline__ int bucket_of(float x) {
    int b = (int)((x - LO0) * BSCALE);   // monotone in x on (LO0, HI0]
    return b < 0 ? 0 : (b > BINS - 1 ? BINS - 1 : b);
}

__global__ __launch_bounds__(NT, 6) void wreg_fused(
    const float* __restrict__ pred,
    const float* __restrict__ tgt,
    float* __restrict__ partial)
{
    __shared__ int   hist[BINS];          // 4 KB
    __shared__ float sval[NT * SSTR];     // 22.5 KB
    __shared__ float redf[NWV];
    __shared__ int   redi[NWV];
    __shared__ int   whi[NWV], wwin[NWV], wovf[NWV], wcnt[NWV], wtot[NWV];
    __shared__ float cands[64];
    __shared__ int   s_nc, s_bstar, s_above;
    __shared__ float s_th;

    const int t = threadIdx.x, lane = t & 63, wid = t >> 6;
    const int bid = blockIdx.x;
    const float4* t4 = reinterpret_cast<const float4*>(tgt)  + (size_t)bid * (HW / 4);
    const float4* p4 = reinterpret_cast<const float4*>(pred) + (size_t)bid * (HW / 4);
    const int sbase = t * SSTR;

    #pragma unroll
    for (int i = t; i < BINS; i += NT) hist[i] = 0;
    if (t == 0) s_nc = 0;

    // ---- Pass 1: stream tgt once (load-and-consume, NO local arrays) ----
    float bmax = -1.f; int bmi = 0;
    int myn = 0;
    unsigned hib = 0u, wib = 0u;          // 1 bit per element (32 elems/thread)
    #pragma unroll
    for (int j = 0; j < V4; ++j) {
        const int vi = j * NT + t;
        float4 v = t4[vi];
        const int base = vi * 4;
        float x;
        x = v.x;
        if (x > bmax) { bmax = x; bmi = base; }
        hib |= (unsigned)(x > HI0) << (j * 4);
        if (x > LO0 && x <= HI0) { wib |= 1u << (j * 4); if (myn < SLOTS) sval[sbase + myn] = x; ++myn; }
        x = v.y;
        if (x > bmax) { bmax = x; bmi = base + 1; }
        hib |= (unsigned)(x > HI0) << (j * 4 + 1);
        if (x > LO0 && x <= HI0) { wib |= 1u << (j * 4 + 1); if (myn < SLOTS) sval[sbase + myn] = x; ++myn; }
        x = v.z;
        if (x > bmax) { bmax = x; bmi = base + 2; }
        hib |= (unsigned)(x > HI0) << (j * 4 + 2);
        if (x > LO0 && x <= HI0) { wib |= 1u << (j * 4 + 2); if (myn < SLOTS) sval[sbase + myn] = x; ++myn; }
        x = v.w;
        if (x > bmax) { bmax = x; bmi = base + 3; }
        hib |= (unsigned)(x > HI0) << (j * 4 + 3);
        if (x > LO0 && x <= HI0) { wib |= 1u << (j * 4 + 3); if (myn < SLOTS) sval[sbase + myn] = x; ++myn; }
    }
    const int mynv = myn > SLOTS ? SLOTS : myn;

    // ---- One combined block reduce: argmax + #(>HI0) + window count + overflow ----
    {
        float am = bmax; int ai = bmi;
        int rh = __popc(hib), rw = myn, ro = (myn > SLOTS) ? 1 : 0;
        #pragma unroll
        for (int off = 32; off > 0; off >>= 1) {
            float ov = __shfl_down(am, off); int ai2 = __shfl_down(ai, off);
            int o1 = __shfl_down(rh, off), o2 = __shfl_down(rw, off), o3 = __shfl_down(ro, off);
            if (ov > am || (ov == am && ai2 < ai)) { am = ov; ai = ai2; }
            rh += o1; rw += o2; ro |= o3;
        }
        if (lane == 0) { redf[wid] = am; redi[wid] = ai; whi[wid] = rh; wwin[wid] = rw; wovf[wid] = ro; }
    }
    __syncthreads();   // also orders hist zeroing before histogram atomics
    float mv = redf[0]; int mi = redi[0];
    int g_hi0 = 0, win = 0, anyovf = 0;
    #pragma unroll
    for (int w = 0; w < NWV; ++w) {
        if (redf[w] > mv || (redf[w] == mv && redi[w] < mi)) { mv = redf[w]; mi = redi[w]; }
        g_hi0 += whi[w]; win += wwin[w]; anyovf |= wovf[w];
    }
    const int need = (GTMAX + 1) - g_hi0;   // rank-from-top within the window
    const bool valid = (!anyovf) && (g_hi0 <= GTMAX) && (need <= win);

    float th = 0.f;
    bool done = false;   // block-uniform throughout

    if (valid) {
        // ---- Counting refinement: histogram stash, suffix-scan, exact tiny rank ----
        for (int k = 0; k < mynv; ++k)
            atomicAdd(&hist[bucket_of(sval[sbase + k])], 1);
        __syncthreads();
        const int h0 = hist[2 * t], h1 = hist[2 * t + 1];
        const int lsum = h0 + h1;
        int incl = lsum;                        // wave suffix-inclusive scan
        #pragma unroll
        for (int off = 1; off < 64; off <<= 1) {
            int v = __shfl_down(incl, off);
            incl += (lane + off < 64) ? v : 0;
        }
        if (lane == 0) wtot[wid] = incl;        // wave total
        __syncthreads();
        int suf = incl - lsum;                  // strictly-higher buckets within my wave
        #pragma unroll
        for (int w = 0; w < NWV; ++w) suf += (w > wid) ? wtot[w] : 0;
        int running = suf;                      // count above bucket 2t+1
        if (running < need && need <= running + h1) { s_bstar = 2 * t + 1; s_above = running; }
        running += h1;                          // count above bucket 2t
        if (running < need && need <= running + h0) { s_bstar = 2 * t;     s_above = running; }
        __syncthreads();
        const int bstar = s_bstar, above = s_above;
        const int cnum = hist[bstar];           // block-uniform
        if (cnum <= 64) {
            for (int k = 0; k < mynv; ++k) {
                float x = sval[sbase + k];
                if (bucket_of(x) == bstar) { int pos = atomicAdd(&s_nc, 1); cands[pos] = x; }
            }
            __syncthreads();
            const int m = s_nc;                 // == cnum, usually 1-2
            for (int i = t; i < m; i += NT) {
                float ci = cands[i];
                int gt = 0, eq = 0;
                for (int j2 = 0; j2 < m; ++j2) {
                    float cj = cands[j2];
                    gt += (cj > ci) ? 1 : 0; eq += (cj == ci) ? 1 : 0;
                }
                int gg = g_hi0 + above + gt;
                if (gg <= GTMAX && gg + eq >= GTMAX + 1) s_th = ci;
            }
            __syncthreads();
            th = s_th;
            done = true;
        }
    }
    const bool fb = !done;
    if (fb) {
        // ---- Exact fallback (rare): value bisection re-reading tgt (cache-hot) ----
        float lo = -1.0f, hi = mv;
        int g_lo = HW, g_hi = 0;
        bool degen = false;
        while (g_lo - g_hi > 48) {
            float mid = 0.5f * (lo + hi);
            if (!(mid > lo && mid < hi)) { degen = true; break; }
            int cnt = 0;
            for (int j = 0; j < V4; ++j) {
                float4 v = t4[j * NT + t];
                cnt += (v.x > mid) + (v.y > mid) + (v.z > mid) + (v.w > mid);
            }
            #pragma unroll
            for (int off = 32; off > 0; off >>= 1) cnt += __shfl_down(cnt, off);
            if (lane == 0) wcnt[wid] = cnt;
            __syncthreads();
            int g = 0;
            #pragma unroll
            for (int w = 0; w < NWV; ++w) g += wcnt[w];
            __syncthreads();
            if (g >= GTMAX + 1) { lo = mid; g_lo = g; }
            else                { hi = mid; g_hi = g; }
        }
        if (degen) th = hi;
        else {
            if (t == 0) s_nc = 0;
            __syncthreads();
            for (int j = 0; j < V4; ++j) {
                float4 v = t4[j * NT + t];
                float x;
                x = v.x; if (x > lo && x <= hi) { int pos = atomicAdd(&s_nc, 1); if (pos < 64) cands[pos] = x; }
                x = v.y; if (x > lo && x <= hi) { int pos = atomicAdd(&s_nc, 1); if (pos < 64) cands[pos] = x; }
                x = v.z; if (x > lo && x <= hi) { int pos = atomicAdd(&s_nc, 1); if (pos < 64) cands[pos] = x; }
                x = v.w; if (x > lo && x <= hi) { int pos = atomicAdd(&s_nc, 1); if (pos < 64) cands[pos] = x; }
            }
            __syncthreads();
            int m = s_nc; m = m > 64 ? 64 : m;
            for (int i = t; i < m; i += NT) {
                float ci = cands[i];
                int gt = 0, eq = 0;
                for (int j2 = 0; j2 < m; ++j2) {
                    float cj = cands[j2];
                    gt += (cj > ci) ? 1 : 0; eq += (cj == ci) ? 1 : 0;
                }
                int gg = g_hi + gt;
                if (gg <= GTMAX && gg + eq >= GTMAX + 1) s_th = ci;
            }
            __syncthreads();
            th = s_th;
        }
    }

    // ---- Pass 2: stream pred once. Mask lives entirely in hib after folding th.
    // Gaussian only within 31x31 box (outside g<=1.3e-14; error ~1e-11, verified).
    const int cyi = mi >> 7, cxi = mi & 127;
    float sum = 0.f;
    if (!fb) {
        // fold stash verdicts into hib (stash order == ascending bit order of wib)
        unsigned wb = wib; int k = 0;
        while (wb) {
            int b = __ffs(wb) - 1;
            wb &= wb - 1u;
            if (sval[sbase + k] > th) hib |= (1u << b);
            ++k;
        }
        #pragma unroll
        for (int j = 0; j < V4; ++j) {
            const int vi = j * NT + t;
            float4 p = p4[vi];
            const unsigned bits = (hib >> (j * 4)) & 0xFu;
            const int base = vi * 4;
            const int dy = (base >> 7) - cyi;
            const int c0 = (base & 127) - cxi;    // dx of component 0
            if ((unsigned)(dy + 15) > 30u || c0 > 15 || c0 + 3 < -15) {
                // off-box group (common): plain p^2 accumulate
                if (bits & 1u) sum = fmaf(p.x, p.x, sum);
                if (bits & 2u) sum = fmaf(p.y, p.y, sum);
                if (bits & 4u) sum = fmaf(p.z, p.z, sum);
                if (bits & 8u) sum = fmaf(p.w, p.w, sum);
            } else {
                const float dy2 = (float)(dy * dy);
                if (bits & 1u) {
                    int dx = c0;     float pv = p.x;
                    if ((unsigned)(dx + 15) <= 30u) { float g = __expf((dy2 + (float)(dx * dx)) * -0.125f); float d = pv - g; sum = fmaf(d, d, sum); }
                    else sum = fmaf(pv, pv, sum);
                }
                if (bits & 2u) {
                    int dx = c0 + 1; float pv = p.y;
                    if ((unsigned)(dx + 15) <= 30u) { float g = __expf((dy2 + (float)(dx * dx)) * -0.125f); float d = pv - g; sum = fmaf(d, d, sum); }
                    else sum = fmaf(pv, pv, sum);
                }
                if (bits & 4u) {
                    int dx = c0 + 2; float pv = p.z;
                    if ((unsigned)(dx + 15) <= 30u) { float g = __expf((dy2 + (float)(dx * dx)) * -0.125f); float d = pv - g; sum = fmaf(d, d, sum); }
                    else sum = fmaf(pv, pv, sum);
                }
                if (bits & 8u) {
                    int dx = c0 + 3; float pv = p.w;
                    if ((unsigned)(dx + 15) <= 30u) { float g = __expf((dy2 + (float)(dx * dx)) * -0.125f); float d = pv - g; sum = fmaf(d, d, sum); }
                    else sum = fmaf(pv, pv, sum);
                }
            }
        }
    } else {
        for (int j = 0; j < V4; ++j) {
            const int vi = j * NT + t;
            float4 tv = t4[vi];
            float4 p  = p4[vi];
            const int base = vi * 4;
            const int dy = (base >> 7) - cyi;
            const int c0 = (base & 127) - cxi;
            const bool boxrow = (unsigned)(dy + 15) <= 30u;
            const float dy2 = (float)(dy * dy);
            if (tv.x > th) { int dx = c0;     float pv = p.x;
                if (boxrow && (unsigned)(dx + 15) <= 30u) { float g = __expf((dy2 + (float)(dx * dx)) * -0.125f); float d = pv - g; sum = fmaf(d, d, sum); }
                else sum = fmaf(pv, pv, sum); }
            if (tv.y > th) { int dx = c0 + 1; float pv = p.y;
                if (boxrow && (unsigned)(dx + 15) <= 30u) { float g = __expf((dy2 + (float)(dx * dx)) * -0.125f); float d = pv - g; sum = fmaf(d, d, sum); }
                else sum = fmaf(pv, pv, sum); }
            if (tv.z > th) { int dx = c0 + 2; float pv = p.z;
                if (boxrow && (unsigned)(dx + 15) <= 30u) { float g = __expf((dy2 + (float)(dx * dx)) * -0.125f); float d = pv - g; sum = fmaf(d, d, sum); }
                else sum = fmaf(pv, pv, sum); }
            if (tv.w > th) { int dx = c0 + 3; float pv = p.w;
                if (boxrow && (unsigned)(dx + 15) <= 30u) { float g = __expf((dy2 + (float)(dx * dx)) * -0.125f); float d = pv - g; sum = fmaf(d, d, sum); }
                else sum = fmaf(pv, pv, sum); }
        }
    }

    // ---- Block reduce, one plain store ----
    #pragma unroll
    for (int off = 32; off > 0; off >>= 1) sum += __shfl_down(sum, off);
    __syncthreads();                 // redf reuse guard
    if (lane == 0) redf[wid] = sum;
    __syncthreads();
    if (t == 0) {
        float s = 0.f;
        #pragma unroll
        for (int w = 0; w < NWV; ++w) s += redf[w];
        partial[bid] = s;
    }
}

__global__ __launch_bounds__(256) void wreg_final(
    const float* __restrict__ partial, float* __restrict__ out)
{
    __shared__ float red[4];
    const int t = threadIdx.x;
    float s = 0.f;
    for (int i = t; i < NSLICE; i += 256) s += partial[i];
    #pragma unroll
    for (int off = 32; off > 0; off >>= 1) s += __shfl_down(s, off);
    if ((t & 63) == 0) red[t >> 6] = s;
    __syncthreads();
    if (t == 0)
        out[0] = ((red[0] + red[1]) + (red[2] + red[3]))
                 * (1.0f / ((float)(HW / 4) * (float)NSLICE));  // / pxl_num / (B*K)
}

extern "C" void kernel_launch(void* const* d_in, const int* in_sizes, int n_in,
                              void* d_out, int out_size, void* d_ws, size_t ws_size,
                              hipStream_t stream)
{
    const float* pred = (const float*)d_in[0];   // "output" in reference
    const float* tgt  = (const float*)d_in[1];   // "target"
    float* partial = (float*)d_ws;               // 1088 floats scratch
    float* out     = (float*)d_out;

    wreg_fused<<<NSLICE, NT, 0, stream>>>(pred, tgt, partial);
    wreg_final<<<1, 256, 0, stream>>>(partial, out);
}